// Round 3
// baseline (2136.225 us; speedup 1.0000x reference)
//
#include <hip/hip_runtime.h>
#include <cstdint>
#include <cmath>

#define DI __device__ __forceinline__

// dims: E=64 S=32 L=32 H=1024 IN=2048 OUT=64; N = E*S = 2048 rows.
// y: [2048][32][1024] bf16, accumulated tap-by-tap across the 32 recurrence steps.
// Wp: packed conv weights [4096][1024] bf16; delta-blocks at col offsets
//     {0,256,768,1536,2560,3328,3840} for delta = -3..3 (active channels = tail).

typedef __attribute__((ext_vector_type(8))) short bf16x8;
typedef __attribute__((ext_vector_type(4))) short s16x4;
typedef __attribute__((ext_vector_type(4))) float f32x4;

DI float bf2f(short u){
  union { unsigned int i; float f; } v; v.i = ((unsigned int)(unsigned short)u) << 16; return v.f;
}
DI short f2bf(float f){
  unsigned int x = __builtin_bit_cast(unsigned int, f);
  unsigned int r = (x + 0x7FFFu + ((x >> 16) & 1u)) >> 16;  // RNE
  return (short)(unsigned short)r;
}
DI void gload16(const void* g, void* l){
  __builtin_amdgcn_global_load_lds(
      (const __attribute__((address_space(1))) unsigned int*)g,
      (__attribute__((address_space(3))) unsigned int*)l, 16, 0, 0);
}

// ---------------------------------------------------------------------------
// bf16 MFMA GEMM (m97 structure): BMxBN tile, BK=64, 256 thr (2x2 waves),
// A row-major [M][K] bf16, Bt = B^T row-major [N][K] bf16, fp32 accum.
// MODE 0: xr = acc + bias[col]                          (f32out, ld 1024)
// MODE 1: recurrence: hn = .5*hf + .5*tanh(xr + acc + bias); hf=hn; bfout=bf16(hn)
// MODE 2: conv-update: y[row, jj-delta, c] += acc  (bf16 RMW; tile skipped if OOR)
// MODE 3: out = acc + bias[col]                         (f32out, ld 64)
// ---------------------------------------------------------------------------
template<int BM, int BN, int MODE>
__global__ __launch_bounds__(256)
void gemm_k(const short* __restrict__ A, long lda,
            const short* __restrict__ Bt, long ldb, int Ksteps,
            const float* __restrict__ bias,
            float* __restrict__ f32out,
            const float* __restrict__ f32in,
            short* __restrict__ bfout, int jj)
{
  constexpr int WTM = BM / 2, WTN = BN / 2;
  constexpr int FM = WTM / 16, FN = WTN / 16;
  __shared__ short As[BM * 64];
  __shared__ short Bs[BN * 64];
  const int tid = threadIdx.x;
  const int w = tid >> 6, l = tid & 63;
  const int wr = w >> 1, wc = w & 1;
  const int lr = l & 15, lk = (l >> 4) << 3;
  const int brow = blockIdx.x * BM;
  const int bcol = blockIdx.y * BN;

  int coff = 0, jout = 0;
  if constexpr (MODE == 2) {
    const int bb = bcol >> 7;
    const int dlt = (bb < 2) ? -3 : (bb < 6) ? -2 : (bb < 12) ? -1
                  : (bb < 20) ? 0 : (bb < 26) ? 1 : (bb < 30) ? 2 : 3;
    coff = (dlt == -3) ? 768 : (dlt == -2) ? 256 : (dlt == -1) ? -512
         : (dlt == 0) ? -1536 : (dlt == 1) ? -2304 : (dlt == 2) ? -2816 : -3072;
    jout = jj - dlt;
    if (jout < 0 || jout > 31) return;   // whole tile out of range (uniform, pre-barrier)
  }

  f32x4 acc[FM][FN];
  #pragma unroll
  for (int i = 0; i < FM; i++)
    #pragma unroll
    for (int j = 0; j < FN; j++) {
      acc[i][j][0] = 0.f; acc[i][j][1] = 0.f; acc[i][j][2] = 0.f; acc[i][j][3] = 0.f;
    }

  for (int ks = 0; ks < Ksteps; ++ks) {
    const short* ab = A + (long)brow * lda + (long)ks * 64;
    #pragma unroll
    for (int it = 0; it < BM / 32; ++it) {
      int ci = it * 256 + tid;
      gload16(ab + (long)(ci >> 3) * lda + ((ci & 7) << 3),
              As + ((it * 256 + (w << 6)) << 3));
    }
    const short* bb2 = Bt + (long)bcol * ldb + (long)ks * 64;
    #pragma unroll
    for (int it = 0; it < BN / 32; ++it) {
      int ci = it * 256 + tid;
      gload16(bb2 + (long)(ci >> 3) * ldb + ((ci & 7) << 3),
              Bs + ((it * 256 + (w << 6)) << 3));
    }
    __syncthreads();
    #pragma unroll
    for (int kk = 0; kk < 64; kk += 32) {
      bf16x8 a[FM], b[FN];
      #pragma unroll
      for (int i = 0; i < FM; i++)
        a[i] = *(const bf16x8*)&As[(wr * WTM + i * 16 + lr) * 64 + kk + lk];
      #pragma unroll
      for (int j = 0; j < FN; j++)
        b[j] = *(const bf16x8*)&Bs[(wc * WTN + j * 16 + lr) * 64 + kk + lk];
      #pragma unroll
      for (int i = 0; i < FM; i++)
        #pragma unroll
        for (int j = 0; j < FN; j++)
          acc[i][j] = __builtin_amdgcn_mfma_f32_16x16x32_bf16(a[i], b[j], acc[i][j], 0, 0, 0);
    }
    __syncthreads();
  }

  // C frag layout: col = l&15, row = (l>>4)*4 + reg  [m89]
  const int rbase = brow + wr * WTM;
  const int cbase = bcol + wc * WTN;
  const int rl = (l >> 4) << 2;
  #pragma unroll
  for (int i = 0; i < FM; i++) {
    #pragma unroll
    for (int j = 0; j < FN; j++) {
      #pragma unroll
      for (int r = 0; r < 4; r++) {
        const int row = rbase + i * 16 + rl + r;
        const int col = cbase + j * 16 + lr;
        const float v = acc[i][j][r];
        if constexpr (MODE == 0) {
          f32out[(long)row * 1024 + col] = v + bias[col];
        } else if constexpr (MODE == 1) {
          const long idx = (long)row * 1024 + col;
          const float hn = 0.5f * f32out[idx] + 0.5f * tanhf(f32in[idx] + v + bias[col]);
          f32out[idx] = hn;
          bfout[idx] = f2bf(hn);
        } else if constexpr (MODE == 2) {
          short* yp = bfout + ((long)row * 32 + jout) * 1024 + (col + coff);
          *yp = f2bf(bf2f(*yp) + v);
        } else {
          f32out[(long)row * 64 + col] = v + bias[col];
        }
      }
    }
  }
}

// ---------------------------------------------------------------------------
// prep / elementwise kernels
// ---------------------------------------------------------------------------
__global__ void zero16(float4* __restrict__ p, long n)
{
  long i = (long)blockIdx.x * 256 + threadIdx.x;
  if (i < n) p[i] = float4{0.f, 0.f, 0.f, 0.f};
}

__global__ void cvt4_f32_bf16(const float* __restrict__ in, short* __restrict__ out, int n4)
{
  int i = blockIdx.x * 256 + threadIdx.x;
  if (i >= n4) return;
  float4 v = ((const float4*)in)[i];
  s16x4 o; o[0] = f2bf(v.x); o[1] = f2bf(v.y); o[2] = f2bf(v.z); o[3] = f2bf(v.w);
  ((s16x4*)out)[i] = o;
}

// f32 [R][C] -> bf16 [C][R]   (R, C multiples of 32)
__global__ void transpose_f32_bf16(const float* __restrict__ in, short* __restrict__ out,
                                   int R, int C)
{
  __shared__ short tile[32][33];
  const int tx = threadIdx.x & 31, ty = threadIdx.x >> 5;
  const int c0 = blockIdx.x * 32, r0 = blockIdx.y * 32;
  #pragma unroll
  for (int i = 0; i < 32; i += 8)
    tile[ty + i][tx] = f2bf(in[(long)(r0 + ty + i) * C + (c0 + tx)]);
  __syncthreads();
  #pragma unroll
  for (int i = 0; i < 32; i += 8)
    out[(long)(c0 + ty + i) * R + (r0 + tx)] = tile[tx][ty + i];
}

// packed conv weights: Wp[pc][i], pc in [0,4096)
__global__ void build_wpack(const float* __restrict__ w1, const float* __restrict__ w3,
                            const float* __restrict__ w5, const float* __restrict__ w7,
                            short* __restrict__ Wp)
{
  const int pc = blockIdx.x;
  int dlt, c;
  if      (pc < 256)  { dlt = -3; c = pc + 768; }
  else if (pc < 768)  { dlt = -2; c = pc + 256; }
  else if (pc < 1536) { dlt = -1; c = pc - 512; }
  else if (pc < 2560) { dlt = 0;  c = pc - 1536; }
  else if (pc < 3328) { dlt = 1;  c = pc - 2304; }
  else if (pc < 3840) { dlt = 2;  c = pc - 2816; }
  else                { dlt = 3;  c = pc - 3072; }
  const int b = c >> 8, kb = 2 * b + 1, t = dlt + b, oo = c & 255;
  const float* w = (b == 0) ? w1 : (b == 1) ? w3 : (b == 2) ? w5 : w7;
  short* dst = Wp + (long)pc * 1024;
  for (int i = threadIdx.x; i < 1024; i += 256)
    dst[i] = f2bf(w[((long)oo * 1024 + i) * kb + t]);
}

__global__ void bn_stats(const short* __restrict__ y, float* __restrict__ sum,
                         float* __restrict__ ssq)
{
  const int c0 = threadIdx.x * 4;
  float s0 = 0, s1 = 0, s2 = 0, s3 = 0, q0 = 0, q1 = 0, q2 = 0, q3 = 0;
  const long base = (long)blockIdx.x * 256;
  for (int r = 0; r < 256; ++r) {
    s16x4 v = *(const s16x4*)(y + (base + r) * 1024 + c0);
    float f0 = bf2f(v[0]), f1 = bf2f(v[1]), f2v = bf2f(v[2]), f3 = bf2f(v[3]);
    s0 += f0; s1 += f1; s2 += f2v; s3 += f3;
    q0 += f0 * f0; q1 += f1 * f1; q2 += f2v * f2v; q3 += f3 * f3;
  }
  atomicAdd(&sum[c0 + 0], s0); atomicAdd(&sum[c0 + 1], s1);
  atomicAdd(&sum[c0 + 2], s2); atomicAdd(&sum[c0 + 3], s3);
  atomicAdd(&ssq[c0 + 0], q0); atomicAdd(&ssq[c0 + 1], q1);
  atomicAdd(&ssq[c0 + 2], q2); atomicAdd(&ssq[c0 + 3], q3);
}

__global__ void bn_finalize(const float* __restrict__ bnsum, const float* __restrict__ bnss,
                            const float* __restrict__ gamma, const float* __restrict__ beta,
                            float* __restrict__ scale, float* __restrict__ shift)
{
  int c = blockIdx.x * 256 + threadIdx.x;
  const float inv = 1.f / 65536.f;
  float mean = bnsum[c] * inv;
  float var = bnss[c] * inv - mean * mean;
  float sc = gamma[c] * rsqrtf(var + 1e-5f);
  scale[c] = sc;
  shift[c] = beta[c] - mean * sc;
}

__global__ void bn_apply(short* __restrict__ y, const float* __restrict__ scale,
                         const float* __restrict__ shift, const float* __restrict__ aP)
{
  const float a = *aP;
  long i = (long)blockIdx.x * 256 + threadIdx.x;   // group of 4 elems
  s16x4 v = ((s16x4*)y)[i];
  int c0 = (int)((i * 4) & 1023);
  #pragma unroll
  for (int j = 0; j < 4; ++j) {
    float f = bf2f(v[j]) * scale[c0 + j] + shift[c0 + j];
    f = f > 0.f ? f : a * f;
    v[j] = f2bf(f);
  }
  ((s16x4*)y)[i] = v;
}

// ---------------------------------------------------------------------------
extern "C" void kernel_launch(void* const* d_in, const int* in_sizes, int n_in,
                              void* d_out, int out_size, void* d_ws, size_t ws_size,
                              hipStream_t stream)
{
  const float* h_w_action = (const float*)d_in[0];
  const float* Wx   = (const float*)d_in[1];
  const float* bx   = (const float*)d_in[2];
  const float* Wh   = (const float*)d_in[3];
  const float* bh   = (const float*)d_in[4];
  const float* w1   = (const float*)d_in[5];
  const float* w3   = (const float*)d_in[7];
  const float* w5   = (const float*)d_in[9];
  const float* w7   = (const float*)d_in[11];
  const float* gamma = (const float*)d_in[13];
  const float* beta  = (const float*)d_in[14];
  const float* prelu = (const float*)d_in[15];
  const float* Wout  = (const float*)d_in[16];
  const float* bout  = (const float*)d_in[17];
  float* out = (float*)d_out;

  char* p = (char*)d_ws;
  auto alloc = [&](size_t bytes) -> char* {
    char* r = p; p += (bytes + 255) & ~(size_t)255; return r;
  };
  short* y     = (short*)alloc(65536L * 1024 * 2);   // 134.2 MB
  float* xr    = (float*)alloc(2048L * 1024 * 4);    // 8 MB
  float* hf    = (float*)alloc(2048L * 1024 * 4);    // 8 MB
  short* hb0   = (short*)alloc(2048L * 1024 * 2);    // 4 MB
  short* hb1   = (short*)alloc(2048L * 1024 * 2);    // 4 MB
  short* A1    = (short*)alloc(2048L * 2048 * 2);    // 8 MB
  short* WxT   = (short*)alloc(1024L * 2048 * 2);    // 4 MB
  short* WhT   = (short*)alloc(1024L * 1024 * 2);    // 2 MB
  short* Wp    = (short*)alloc(4096L * 1024 * 2);    // 8 MB
  short* WoutT = (short*)alloc(64L * 1024 * 2);
  float* bnsum = (float*)alloc(1024 * 4);
  float* bnss  = (float*)alloc(1024 * 4);
  float* scal  = (float*)alloc(1024 * 4);
  float* shft  = (float*)alloc(1024 * 4);

  if ((size_t)(p - (char*)d_ws) > ws_size) return;   // ws too small -> clean fail (diagnostic)

  // zero-init: y, hf, hb0, bn accumulators
  zero16<<<32768, 256, 0, stream>>>((float4*)y, 65536L * 1024 * 2 / 16);
  zero16<<<2048, 256, 0, stream>>>((float4*)hf, 2048L * 1024 * 4 / 16);
  zero16<<<1024, 256, 0, stream>>>((float4*)hb0, 2048L * 1024 * 2 / 16);
  zero16<<<1, 256, 0, stream>>>((float4*)bnsum, 256);
  zero16<<<1, 256, 0, stream>>>((float4*)bnss, 256);

  // prep
  cvt4_f32_bf16<<<4096, 256, 0, stream>>>(h_w_action, A1, 2048 * 2048 / 4);
  transpose_f32_bf16<<<dim3(32, 64), 256, 0, stream>>>(Wx, WxT, 2048, 1024);
  transpose_f32_bf16<<<dim3(32, 32), 256, 0, stream>>>(Wh, WhT, 1024, 1024);
  transpose_f32_bf16<<<dim3(2, 32), 256, 0, stream>>>(Wout, WoutT, 1024, 64);
  build_wpack<<<4096, 256, 0, stream>>>(w1, w3, w5, w7, Wp);

  // G1: xr = X @ Wx + bx   [2048 x 1024], K=2048
  gemm_k<128, 128, 0><<<dim3(16, 8), 256, 0, stream>>>(
      A1, 2048, WxT, 2048, 32, bx, xr, nullptr, nullptr, 0);

  // recurrence + fused conv scatter: step s produces h_s; conv uses hs_j (j=s-1)
  short* hb[2] = {hb0, hb1};
  for (int s = 1; s <= 32; ++s) {
    gemm_k<64, 128, 1><<<dim3(32, 8), 256, 0, stream>>>(
        hb[(s - 1) & 1], 1024, WhT, 1024, 16, bh, hf, xr, hb[s & 1], 0);
    gemm_k<128, 128, 2><<<dim3(16, 32), 256, 0, stream>>>(
        hb[s & 1], 1024, Wp, 1024, 16, nullptr, nullptr, nullptr, y, s - 1);
  }

  // BN (batch stats; conv bias absorbed by mean subtraction) + PReLU, in place
  bn_stats<<<256, 256, 0, stream>>>(y, bnsum, bnss);
  bn_finalize<<<4, 256, 0, stream>>>(bnsum, bnss, gamma, beta, scal, shft);
  bn_apply<<<65536, 256, 0, stream>>>(y, scal, shft, prelu);

  // G5: out = y @ Wout + bout  [65536 x 64]
  gemm_k<128, 64, 3><<<dim3(512, 1), 256, 0, stream>>>(
      y, 1024, WoutT, 1024, 16, bout, out, nullptr, nullptr, 0);
}

// Round 4
// 2043.505 us; speedup vs baseline: 1.0454x; 1.0454x over previous
//
#include <hip/hip_runtime.h>
#include <cstdint>
#include <cmath>

#define DI __device__ __forceinline__

// dims: E=64 S=32 L=32 H=1024 IN=2048 OUT=64; N = E*S = 2048 rows.
// y: [2048][32][1024] bf16, accumulated tap-by-tap across the 32 recurrence steps.
// Wp: packed conv weights [4096][1024] bf16; delta-blocks at col offsets
//     {0,256,768,1536,2560,3328,3840} for delta = -3..3 (active channels = tail).

typedef __attribute__((ext_vector_type(8))) short bf16x8;
typedef __attribute__((ext_vector_type(4))) short s16x4;
typedef __attribute__((ext_vector_type(4))) float f32x4;

DI float bf2f(short u){
  union { unsigned int i; float f; } v; v.i = ((unsigned int)(unsigned short)u) << 16; return v.f;
}
DI short f2bf(float f){
  unsigned int x = __builtin_bit_cast(unsigned int, f);
  unsigned int r = (x + 0x7FFFu + ((x >> 16) & 1u)) >> 16;  // RNE
  return (short)(unsigned short)r;
}
DI void gload16(const void* g, void* l){
  __builtin_amdgcn_global_load_lds(
      (const __attribute__((address_space(1))) unsigned int*)g,
      (__attribute__((address_space(3))) unsigned int*)l, 16, 0, 0);
}

// ---------------------------------------------------------------------------
// bf16 MFMA GEMM (m97 structure + hoisted staging pointers): BMxBN tile, BK=64,
// 256 thr (2x2 waves), A row-major [M][K] bf16, Bt=B^T [N][K] bf16, fp32 accum.
// MODE 0: xr = acc + bias[col]                          (f32out, ld 1024)
// MODE 1: recurrence: hn = .5*hf + .5*tanh(xr + acc + bias); hf=hn; bfout=bf16(hn)
// MODE 2: conv-update: y[row, jj-delta, c] += acc  (bf16 RMW; tile skipped if OOR)
// MODE 3: out = acc + bias[col]                         (f32out, ld 64)
// ---------------------------------------------------------------------------
template<int BM, int BN, int MODE>
__global__ __launch_bounds__(256)
void gemm_k(const short* __restrict__ A, long lda,
            const short* __restrict__ Bt, long ldb, int Ksteps,
            const float* __restrict__ bias,
            float* __restrict__ f32out,
            const float* __restrict__ f32in,
            short* __restrict__ bfout, int jj)
{
  constexpr int WTM = BM / 2, WTN = BN / 2;
  constexpr int FM = WTM / 16, FN = WTN / 16;
  constexpr int AIT = BM / 32, BIT = BN / 32;
  __shared__ short As[BM * 64];
  __shared__ short Bs[BN * 64];
  const int tid = threadIdx.x;
  const int w = tid >> 6, l = tid & 63;
  const int wr = w >> 1, wc = w & 1;
  const int lr = l & 15, lk = (l >> 4) << 3;
  const int brow = blockIdx.x * BM;
  const int bcol = blockIdx.y * BN;

  int coff = 0, jout = 0;
  if constexpr (MODE == 2) {
    const int bb = bcol >> 7;
    const int dlt = (bb < 2) ? -3 : (bb < 6) ? -2 : (bb < 12) ? -1
                  : (bb < 20) ? 0 : (bb < 26) ? 1 : (bb < 30) ? 2 : 3;
    coff = (dlt == -3) ? 768 : (dlt == -2) ? 256 : (dlt == -1) ? -512
         : (dlt == 0) ? -1536 : (dlt == 1) ? -2304 : (dlt == 2) ? -2816 : -3072;
    jout = jj - dlt;
    if (jout < 0 || jout > 31) return;   // whole tile out of range (uniform, pre-barrier)
  }

  f32x4 acc[FM][FN];
  #pragma unroll
  for (int i = 0; i < FM; i++)
    #pragma unroll
    for (int j = 0; j < FN; j++) {
      acc[i][j][0] = 0.f; acc[i][j][1] = 0.f; acc[i][j][2] = 0.f; acc[i][j][3] = 0.f;
    }

  // hoisted per-iterator staging pointers (advance by BK=64 shorts per K-step)
  const short* ap[AIT];
  const short* bp[BIT];
  const int rsub = tid >> 3;              // 0..31
  const int koff = (tid & 7) << 3;        // 0,8,..,56 shorts
  #pragma unroll
  for (int it = 0; it < AIT; ++it)
    ap[it] = A + (long)(brow + it * 32 + rsub) * lda + koff;
  #pragma unroll
  for (int it = 0; it < BIT; ++it)
    bp[it] = Bt + (long)(bcol + it * 32 + rsub) * ldb + koff;

  for (int ks = 0; ks < Ksteps; ++ks) {
    #pragma unroll
    for (int it = 0; it < AIT; ++it) {
      gload16(ap[it], As + ((it * 256 + (w << 6)) << 3));
      ap[it] += 64;
    }
    #pragma unroll
    for (int it = 0; it < BIT; ++it) {
      gload16(bp[it], Bs + ((it * 256 + (w << 6)) << 3));
      bp[it] += 64;
    }
    __syncthreads();
    #pragma unroll
    for (int kk = 0; kk < 64; kk += 32) {
      bf16x8 a[FM], b[FN];
      #pragma unroll
      for (int i = 0; i < FM; i++)
        a[i] = *(const bf16x8*)&As[(wr * WTM + i * 16 + lr) * 64 + kk + lk];
      #pragma unroll
      for (int j = 0; j < FN; j++)
        b[j] = *(const bf16x8*)&Bs[(wc * WTN + j * 16 + lr) * 64 + kk + lk];
      #pragma unroll
      for (int i = 0; i < FM; i++)
        #pragma unroll
        for (int j = 0; j < FN; j++)
          acc[i][j] = __builtin_amdgcn_mfma_f32_16x16x32_bf16(a[i], b[j], acc[i][j], 0, 0, 0);
    }
    __syncthreads();
  }

  // C frag layout: col = l&15, row = (l>>4)*4 + reg  [m89]
  const int rbase = brow + wr * WTM;
  const int cbase = bcol + wc * WTN;
  const int rl = (l >> 4) << 2;
  #pragma unroll
  for (int i = 0; i < FM; i++) {
    #pragma unroll
    for (int j = 0; j < FN; j++) {
      #pragma unroll
      for (int r = 0; r < 4; r++) {
        const int row = rbase + i * 16 + rl + r;
        const int col = cbase + j * 16 + lr;
        const float v = acc[i][j][r];
        if constexpr (MODE == 0) {
          f32out[(long)row * 1024 + col] = v + bias[col];
        } else if constexpr (MODE == 1) {
          const long idx = (long)row * 1024 + col;
          const float hn = 0.5f * f32out[idx] + 0.5f * tanhf(f32in[idx] + v + bias[col]);
          f32out[idx] = hn;
          bfout[idx] = f2bf(hn);
        } else if constexpr (MODE == 2) {
          short* yp = bfout + ((long)row * 32 + jout) * 1024 + (col + coff);
          *yp = f2bf(bf2f(*yp) + v);
        } else {
          f32out[(long)row * 64 + col] = v + bias[col];
        }
      }
    }
  }
}

// ---------------------------------------------------------------------------
// G5 with fused BatchNorm scale/shift + PReLU on the A operand (reg-staged):
// out[m][0:64] = prelu(bn(y[m][:])) @ WoutT + bout.   BM=128, BN=64, K=1024.
// ---------------------------------------------------------------------------
__global__ __launch_bounds__(256)
void g5_bn(const short* __restrict__ y, const short* __restrict__ WoutT,
           const float* __restrict__ scal, const float* __restrict__ shft,
           const float* __restrict__ aP, const float* __restrict__ bout,
           float* __restrict__ out)
{
  __shared__ short As[128 * 64];
  __shared__ short Bs[64 * 64];
  __shared__ float sS[1024], sB[1024];
  const int tid = threadIdx.x;
  const int w = tid >> 6, l = tid & 63;
  const int wr = w >> 1, wc = w & 1;
  const int lr = l & 15, lk = (l >> 4) << 3;
  const int m0 = blockIdx.x * 128;
  for (int i = tid; i < 1024; i += 256) { sS[i] = scal[i]; sB[i] = shft[i]; }
  const float a = *aP;
  __syncthreads();

  f32x4 acc[4][2];
  #pragma unroll
  for (int i = 0; i < 4; i++)
    #pragma unroll
    for (int j = 0; j < 2; j++) {
      acc[i][j][0] = 0.f; acc[i][j][1] = 0.f; acc[i][j][2] = 0.f; acc[i][j][3] = 0.f;
    }

  const int rsub = tid >> 3;
  const int koff = (tid & 7) << 3;
  const short* yp[4];
  #pragma unroll
  for (int it = 0; it < 4; ++it)
    yp[it] = y + (long)(m0 + it * 32 + rsub) * 1024 + koff;
  const short* bp[2];
  #pragma unroll
  for (int it = 0; it < 2; ++it)
    bp[it] = WoutT + (long)(it * 32 + rsub) * 1024 + koff;

  for (int ks = 0; ks < 16; ++ks) {
    #pragma unroll
    for (int it = 0; it < 2; ++it) {
      gload16(bp[it], Bs + ((it * 256 + (w << 6)) << 3));
      bp[it] += 64;
    }
    const int c0 = ks * 64 + koff;
    #pragma unroll
    for (int it = 0; it < 4; ++it) {
      bf16x8 v = *(const bf16x8*)yp[it];
      yp[it] += 64;
      #pragma unroll
      for (int e = 0; e < 8; ++e) {
        float f = bf2f(v[e]) * sS[c0 + e] + sB[c0 + e];
        v[e] = f2bf(f > 0.f ? f : a * f);
      }
      *(bf16x8*)(As + ((it * 256 + tid) << 3)) = v;
    }
    __syncthreads();
    #pragma unroll
    for (int kk = 0; kk < 64; kk += 32) {
      bf16x8 af[4], bf_[2];
      #pragma unroll
      for (int i = 0; i < 4; i++)
        af[i] = *(const bf16x8*)&As[(wr * 64 + i * 16 + lr) * 64 + kk + lk];
      #pragma unroll
      for (int j = 0; j < 2; j++)
        bf_[j] = *(const bf16x8*)&Bs[(wc * 32 + j * 16 + lr) * 64 + kk + lk];
      #pragma unroll
      for (int i = 0; i < 4; i++)
        #pragma unroll
        for (int j = 0; j < 2; j++)
          acc[i][j] = __builtin_amdgcn_mfma_f32_16x16x32_bf16(af[i], bf_[j], acc[i][j], 0, 0, 0);
    }
    __syncthreads();
  }

  const int rbase = m0 + wr * 64, cbase = wc * 32;
  const int rl = (l >> 4) << 2;
  #pragma unroll
  for (int i = 0; i < 4; i++)
    #pragma unroll
    for (int j = 0; j < 2; j++)
      #pragma unroll
      for (int r = 0; r < 4; r++) {
        const int row = rbase + i * 16 + rl + r;
        const int col = cbase + j * 16 + lr;
        out[(long)row * 64 + col] = acc[i][j][r] + bout[col];
      }
}

// ---------------------------------------------------------------------------
// prep / elementwise kernels
// ---------------------------------------------------------------------------
__global__ void zero16(float4* __restrict__ p, long n)
{
  long i = (long)blockIdx.x * 256 + threadIdx.x;
  if (i < n) p[i] = float4{0.f, 0.f, 0.f, 0.f};
}

__global__ void cvt4_f32_bf16(const float* __restrict__ in, short* __restrict__ out, int n4)
{
  int i = blockIdx.x * 256 + threadIdx.x;
  if (i >= n4) return;
  float4 v = ((const float4*)in)[i];
  s16x4 o; o[0] = f2bf(v.x); o[1] = f2bf(v.y); o[2] = f2bf(v.z); o[3] = f2bf(v.w);
  ((s16x4*)out)[i] = o;
}

// f32 [R][C] -> bf16 [C][R]   (R, C multiples of 32)
__global__ void transpose_f32_bf16(const float* __restrict__ in, short* __restrict__ out,
                                   int R, int C)
{
  __shared__ short tile[32][33];
  const int tx = threadIdx.x & 31, ty = threadIdx.x >> 5;
  const int c0 = blockIdx.x * 32, r0 = blockIdx.y * 32;
  #pragma unroll
  for (int i = 0; i < 32; i += 8)
    tile[ty + i][tx] = f2bf(in[(long)(r0 + ty + i) * C + (c0 + tx)]);
  __syncthreads();
  #pragma unroll
  for (int i = 0; i < 32; i += 8)
    out[(long)(c0 + ty + i) * R + (r0 + tx)] = tile[tx][ty + i];
}

// packed conv weights: Wp[pc][i], pc in [0,4096)
__global__ void build_wpack(const float* __restrict__ w1, const float* __restrict__ w3,
                            const float* __restrict__ w5, const float* __restrict__ w7,
                            short* __restrict__ Wp)
{
  const int pc = blockIdx.x;
  int dlt, c;
  if      (pc < 256)  { dlt = -3; c = pc + 768; }
  else if (pc < 768)  { dlt = -2; c = pc + 256; }
  else if (pc < 1536) { dlt = -1; c = pc - 512; }
  else if (pc < 2560) { dlt = 0;  c = pc - 1536; }
  else if (pc < 3328) { dlt = 1;  c = pc - 2304; }
  else if (pc < 3840) { dlt = 2;  c = pc - 2816; }
  else                { dlt = 3;  c = pc - 3072; }
  const int b = c >> 8, kb = 2 * b + 1, t = dlt + b, oo = c & 255;
  const float* w = (b == 0) ? w1 : (b == 1) ? w3 : (b == 2) ? w5 : w7;
  short* dst = Wp + (long)pc * 1024;
  for (int i = threadIdx.x; i < 1024; i += 256)
    dst[i] = f2bf(w[((long)oo * 1024 + i) * kb + t]);
}

// full-occupancy stats: 2048 blocks x 32 rows; one atomic per (channel,stat) per block
__global__ void bn_stats(const short* __restrict__ y, float* __restrict__ sum,
                         float* __restrict__ ssq)
{
  const int c0 = threadIdx.x * 4;
  float s0 = 0, s1 = 0, s2 = 0, s3 = 0, q0 = 0, q1 = 0, q2 = 0, q3 = 0;
  const long base = (long)blockIdx.x * 32;
  for (int r = 0; r < 32; ++r) {
    s16x4 v = *(const s16x4*)(y + (base + r) * 1024 + c0);
    float f0 = bf2f(v[0]), f1 = bf2f(v[1]), f2v = bf2f(v[2]), f3 = bf2f(v[3]);
    s0 += f0; s1 += f1; s2 += f2v; s3 += f3;
    q0 += f0 * f0; q1 += f1 * f1; q2 += f2v * f2v; q3 += f3 * f3;
  }
  atomicAdd(&sum[c0 + 0], s0); atomicAdd(&sum[c0 + 1], s1);
  atomicAdd(&sum[c0 + 2], s2); atomicAdd(&sum[c0 + 3], s3);
  atomicAdd(&ssq[c0 + 0], q0); atomicAdd(&ssq[c0 + 1], q1);
  atomicAdd(&ssq[c0 + 2], q2); atomicAdd(&ssq[c0 + 3], q3);
}

__global__ void bn_finalize(const float* __restrict__ bnsum, const float* __restrict__ bnss,
                            const float* __restrict__ gamma, const float* __restrict__ beta,
                            float* __restrict__ scale, float* __restrict__ shift)
{
  int c = blockIdx.x * 256 + threadIdx.x;
  const float inv = 1.f / 65536.f;
  float mean = bnsum[c] * inv;
  float var = bnss[c] * inv - mean * mean;
  float sc = gamma[c] * rsqrtf(var + 1e-5f);
  scale[c] = sc;
  shift[c] = beta[c] - mean * sc;
}

// ---------------------------------------------------------------------------
extern "C" void kernel_launch(void* const* d_in, const int* in_sizes, int n_in,
                              void* d_out, int out_size, void* d_ws, size_t ws_size,
                              hipStream_t stream)
{
  const float* h_w_action = (const float*)d_in[0];
  const float* Wx   = (const float*)d_in[1];
  const float* bx   = (const float*)d_in[2];
  const float* Wh   = (const float*)d_in[3];
  const float* bh   = (const float*)d_in[4];
  const float* w1   = (const float*)d_in[5];
  const float* w3   = (const float*)d_in[7];
  const float* w5   = (const float*)d_in[9];
  const float* w7   = (const float*)d_in[11];
  const float* gamma = (const float*)d_in[13];
  const float* beta  = (const float*)d_in[14];
  const float* prelu = (const float*)d_in[15];
  const float* Wout  = (const float*)d_in[16];
  const float* bout  = (const float*)d_in[17];
  float* out = (float*)d_out;

  char* p = (char*)d_ws;
  auto alloc = [&](size_t bytes) -> char* {
    char* r = p; p += (bytes + 255) & ~(size_t)255; return r;
  };
  short* y     = (short*)alloc(65536L * 1024 * 2);   // 134.2 MB
  float* xr    = (float*)alloc(2048L * 1024 * 4);    // 8 MB
  float* hf    = (float*)alloc(2048L * 1024 * 4);    // 8 MB
  short* hb0   = (short*)alloc(2048L * 1024 * 2);    // 4 MB
  short* hb1   = (short*)alloc(2048L * 1024 * 2);    // 4 MB
  short* A1    = (short*)alloc(2048L * 2048 * 2);    // 8 MB
  short* WxT   = (short*)alloc(1024L * 2048 * 2);    // 4 MB
  short* WhT   = (short*)alloc(1024L * 1024 * 2);    // 2 MB
  short* Wp    = (short*)alloc(4096L * 1024 * 2);    // 8 MB
  short* WoutT = (short*)alloc(64L * 1024 * 2);
  float* bnsum = (float*)alloc(1024 * 4);
  float* bnss  = (float*)alloc(1024 * 4);
  float* scal  = (float*)alloc(1024 * 4);
  float* shft  = (float*)alloc(1024 * 4);

  if ((size_t)(p - (char*)d_ws) > ws_size) return;   // ws too small -> clean fail (diagnostic)

  // zero-init: y, hf, hb0, bn accumulators
  zero16<<<32768, 256, 0, stream>>>((float4*)y, 65536L * 1024 * 2 / 16);
  zero16<<<2048, 256, 0, stream>>>((float4*)hf, 2048L * 1024 * 4 / 16);
  zero16<<<1024, 256, 0, stream>>>((float4*)hb0, 2048L * 1024 * 2 / 16);
  zero16<<<1, 256, 0, stream>>>((float4*)bnsum, 256);
  zero16<<<1, 256, 0, stream>>>((float4*)bnss, 256);

  // prep
  cvt4_f32_bf16<<<4096, 256, 0, stream>>>(h_w_action, A1, 2048 * 2048 / 4);
  transpose_f32_bf16<<<dim3(32, 64), 256, 0, stream>>>(Wx, WxT, 2048, 1024);
  transpose_f32_bf16<<<dim3(32, 32), 256, 0, stream>>>(Wh, WhT, 1024, 1024);
  transpose_f32_bf16<<<dim3(2, 32), 256, 0, stream>>>(Wout, WoutT, 1024, 64);
  build_wpack<<<4096, 256, 0, stream>>>(w1, w3, w5, w7, Wp);

  // G1: xr = X @ Wx + bx   [2048 x 1024], K=2048  (256 blocks)
  gemm_k<64, 128, 0><<<dim3(32, 8), 256, 0, stream>>>(
      A1, 2048, WxT, 2048, 32, bx, xr, nullptr, nullptr, 0);

  // recurrence + fused conv scatter: step s produces h_s; conv uses h_s (j=s-1)
  short* hb[2] = {hb0, hb1};
  for (int s = 1; s <= 32; ++s) {
    gemm_k<64, 64, 1><<<dim3(32, 16), 256, 0, stream>>>(
        hb[(s - 1) & 1], 1024, WhT, 1024, 16, bh, hf, xr, hb[s & 1], 0);
    gemm_k<128, 128, 2><<<dim3(16, 32), 256, 0, stream>>>(
        hb[s & 1], 1024, Wp, 1024, 16, nullptr, nullptr, nullptr, y, s - 1);
  }

  // BN batch stats (conv bias absorbed by mean subtraction)
  bn_stats<<<2048, 256, 0, stream>>>(y, bnsum, bnss);
  bn_finalize<<<4, 256, 0, stream>>>(bnsum, bnss, gamma, beta, scal, shft);

  // G5 with fused BN scale/shift + PReLU on A:  out = prelu(bn(y)) @ Wout + bout
  g5_bn<<<dim3(512, 1), 256, 0, stream>>>(y, WoutT, scal, shft, prelu, bout, out);
}